// Round 3
// baseline (322.724 us; speedup 1.0000x reference)
//
#include <hip/hip_runtime.h>
#include <hip/hip_bf16.h>

// CapsuleLayer dynamic routing, B=512, P=1152, N=10, T=16, D=8, 3 iters. fp32.
// Round-3 structure: ALL-GLOBAL kernels (no LDS staging, no barriers in hot
// loops) — inputs are L2/L3-resident, so L1/L2 feed the FMA loop directly.
// s-reduction via per-p-tile partials in d_ws (no atomics); softmax fused
// into k_s; squash fused with the partial reduction in k_v.
// Fallback: if ws_size < 32 MB, use round-2's atomicAdd path (mode 0).

constexpr int B_ = 512;
constexpr int P_ = 1152;
constexpr int N_ = 10;
constexpr int T_ = 16;
constexpr int NT_ = 160;
constexpr int PTILES_ = 96;   // k_s grid.y; 12 p per tile
constexpr int SPART_FLOATS_ = (size_t)PTILES_ * B_ * NT_;  // 7.86M floats

// ---------------------------------------------------------------------------
// k_s: s_part[py][b][nt] = sum_{p in tile} c[p,n] * (sum_d W[p,nt,d] x[b,p,d])
// grid (8, 96), 256 thr: col=tid&15 (=t), bg=tid>>4; thread owns 4 b, all n.
// Softmax over n fused at block start (reads bbar, 12 rows per block).
__global__ __launch_bounds__(256, 3) void k_s(const float* __restrict__ x,
                                              const float* __restrict__ W,
                                              const float* __restrict__ bbar,
                                              float* __restrict__ spart,
                                              float* __restrict__ s_atomic,
                                              int mode) {
    __shared__ float cs[12][N_];
    const int tid = threadIdx.x;
    const int col = tid & 15;
    const int bg  = tid >> 4;
    const int b0 = blockIdx.x * 64;
    const int py = blockIdx.y;
    const int p0 = py * 12;

    if (tid < 12) {
        float bv[N_], m = -1e30f;
#pragma unroll
        for (int n = 0; n < N_; ++n) { bv[n] = bbar[(p0 + tid) * N_ + n]; m = fmaxf(m, bv[n]); }
        float sum = 0.f;
#pragma unroll
        for (int n = 0; n < N_; ++n) { bv[n] = expf(bv[n] - m); sum += bv[n]; }
        const float inv = 1.f / sum;
#pragma unroll
        for (int n = 0; n < N_; ++n) cs[tid][n] = bv[n] * inv;
    }
    __syncthreads();

    float acc[N_][4];
#pragma unroll
    for (int n = 0; n < N_; ++n)
#pragma unroll
        for (int j = 0; j < 4; ++j) acc[n][j] = 0.f;

    for (int pp = 0; pp < 12; ++pp) {
        const int p = p0 + pp;
        float xr[4][8];
#pragma unroll
        for (int j = 0; j < 4; ++j) {
            const float* g = x + ((size_t)(b0 + bg * 4 + j) * P_ + p) * 8;
            float4 a = *(const float4*)g;
            float4 b = *(const float4*)(g + 4);
            xr[j][0] = a.x; xr[j][1] = a.y; xr[j][2] = a.z; xr[j][3] = a.w;
            xr[j][4] = b.x; xr[j][5] = b.y; xr[j][6] = b.z; xr[j][7] = b.w;
        }
#pragma unroll
        for (int n = 0; n < N_; ++n) {
            const float* g = W + ((size_t)p * NT_ + n * 16 + col) * 8;
            const float4 wa = *(const float4*)g;
            const float4 wb = *(const float4*)(g + 4);
            const float cn = cs[pp][n];
#pragma unroll
            for (int j = 0; j < 4; ++j) {
                float pred = wa.x * xr[j][0];
                pred = fmaf(wa.y, xr[j][1], pred);
                pred = fmaf(wa.z, xr[j][2], pred);
                pred = fmaf(wa.w, xr[j][3], pred);
                pred = fmaf(wb.x, xr[j][4], pred);
                pred = fmaf(wb.y, xr[j][5], pred);
                pred = fmaf(wb.z, xr[j][6], pred);
                pred = fmaf(wb.w, xr[j][7], pred);
                acc[n][j] = fmaf(cn, pred, acc[n][j]);
            }
        }
    }

    if (mode) {
        float* dst = spart + (size_t)py * B_ * NT_;
#pragma unroll
        for (int n = 0; n < N_; ++n)
#pragma unroll
            for (int j = 0; j < 4; ++j)
                dst[(size_t)(b0 + bg * 4 + j) * NT_ + n * 16 + col] = acc[n][j];
    } else {
#pragma unroll
        for (int n = 0; n < N_; ++n)
#pragma unroll
            for (int j = 0; j < 4; ++j)
                atomicAdd(&s_atomic[(size_t)(b0 + bg * 4 + j) * NT_ + n * 16 + col], acc[n][j]);
    }
}

// ---------------------------------------------------------------------------
// k_v: reduce 96 partials (mode 1) or read s (mode 0), then squash; writes v
// or (final iter) d_out. thread = (b, n, tq): one float4 (4 t's) per thread.
__global__ __launch_bounds__(256) void k_v(const float* __restrict__ sp,
                                           float* __restrict__ out,
                                           int mode) {
    const int t = blockIdx.x * blockDim.x + threadIdx.x;  // 20480 threads
    const int tq = t & 3;
    const int n  = (t >> 2) % N_;
    const int b  = t / (N_ * 4);
    const size_t base = (size_t)b * NT_ + n * 16 + tq * 4;

    float4 a = make_float4(0.f, 0.f, 0.f, 0.f);
    if (mode) {
#pragma unroll
        for (int py = 0; py < PTILES_; ++py) {
            const float4 u = *(const float4*)(sp + (size_t)py * B_ * NT_ + base);
            a.x += u.x; a.y += u.y; a.z += u.z; a.w += u.w;
        }
    } else {
        a = *(const float4*)(sp + base);
    }
    float sq = a.x * a.x + a.y * a.y + a.z * a.z + a.w * a.w;
    sq += __shfl_xor(sq, 1);
    sq += __shfl_xor(sq, 2);
    const float norm = sqrtf(sq);
    const float scale = sq / (1.0f + sq * (norm + 1e-9f));
    a.x *= scale; a.y *= scale; a.z *= scale; a.w *= scale;
    *(float4*)(out + base) = a;
}

// ---------------------------------------------------------------------------
// k_a: bbar[p,n] += (1/B) sum_{b,t} (sum_d W[p,nt,d] x[b,p,d]) * v[b,nt]
// grid (144, 8): 8 p x 64 b per block. thread (pl=tid>>5, r=tid&31) holds
// W rows nt=r+32k (k<5) in registers; v and x read straight from global.
__global__ __launch_bounds__(256, 4) void k_a(const float* __restrict__ x,
                                              const float* __restrict__ W,
                                              const float* __restrict__ v,
                                              float* __restrict__ bbar) {
    const int tid = threadIdx.x;
    const int pl = tid >> 5;
    const int r  = tid & 31;
    const int p  = blockIdx.x * 8 + pl;
    const int b0 = blockIdx.y * 64;

    float wreg[5][8];
#pragma unroll
    for (int k = 0; k < 5; ++k) {
        const float* g = W + ((size_t)p * NT_ + (r + 32 * k)) * 8;
        float4 a = *(const float4*)g;
        float4 b = *(const float4*)(g + 4);
        wreg[k][0] = a.x; wreg[k][1] = a.y; wreg[k][2] = a.z; wreg[k][3] = a.w;
        wreg[k][4] = b.x; wreg[k][5] = b.y; wreg[k][6] = b.z; wreg[k][7] = b.w;
    }
    float acc[5] = {0.f, 0.f, 0.f, 0.f, 0.f};

#pragma unroll 4
    for (int bb = 0; bb < 64; ++bb) {
        const int b = b0 + bb;
        const float* gx = x + ((size_t)b * P_ + p) * 8;
        float4 a  = *(const float4*)gx;
        float4 b2 = *(const float4*)(gx + 4);
        const float xv[8] = {a.x, a.y, a.z, a.w, b2.x, b2.y, b2.z, b2.w};
        const float* gv = v + (size_t)b * NT_ + r;
        float vv[5];
#pragma unroll
        for (int k = 0; k < 5; ++k) vv[k] = gv[32 * k];
#pragma unroll
        for (int k = 0; k < 5; ++k) {
            float pred = wreg[k][0] * xv[0];
            pred = fmaf(wreg[k][1], xv[1], pred);
            pred = fmaf(wreg[k][2], xv[2], pred);
            pred = fmaf(wreg[k][3], xv[3], pred);
            pred = fmaf(wreg[k][4], xv[4], pred);
            pred = fmaf(wreg[k][5], xv[5], pred);
            pred = fmaf(wreg[k][6], xv[6], pred);
            pred = fmaf(wreg[k][7], xv[7], pred);
            acc[k] = fmaf(pred, vv[k], acc[k]);
        }
    }
#pragma unroll
    for (int off = 1; off < 16; off <<= 1)
#pragma unroll
        for (int k = 0; k < 5; ++k) acc[k] += __shfl_xor(acc[k], off);
    if ((tid & 15) == 0) {
#pragma unroll
        for (int k = 0; k < 5; ++k) {
            const int n = ((tid >> 4) & 1) + 2 * k;
            atomicAdd(&bbar[(size_t)p * N_ + n], acc[k] * (1.0f / 512.0f));
        }
    }
}

extern "C" void kernel_launch(void* const* d_in, const int* in_sizes, int n_in,
                              void* d_out, int out_size, void* d_ws, size_t ws_size,
                              hipStream_t stream) {
    const float* x = (const float*)d_in[0];  // fp32 [B,P,D]
    const float* W = (const float*)d_in[1];  // fp32 [P,N,T,D]

    float* bbar = (float*)d_ws;                       // 11520
    float* v    = bbar + (size_t)P_ * N_;             // 81920
    float* sbuf = v + (size_t)B_ * NT_;               // partials (31.5 MB) or s (328 KB)

    const size_t need = ((size_t)P_ * N_ + (size_t)B_ * NT_ + SPART_FLOATS_) * sizeof(float);
    const int mode = (ws_size >= need) ? 1 : 0;

    hipMemsetAsync(bbar, 0, (size_t)P_ * N_ * sizeof(float), stream);

    for (int it = 0; it < 3; ++it) {
        if (!mode) hipMemsetAsync(sbuf, 0, (size_t)B_ * NT_ * sizeof(float), stream);
        k_s<<<dim3(8, PTILES_), dim3(256), 0, stream>>>(x, W, bbar, sbuf, sbuf, mode);
        float* vout = (it < 2) ? v : (float*)d_out;
        k_v<<<dim3(80), dim3(256), 0, stream>>>(sbuf, vout, mode);
        if (it < 2)
            k_a<<<dim3(144, 8), dim3(256), 0, stream>>>(x, W, v, bbar);
    }
}

// Round 4
// 209.108 us; speedup vs baseline: 1.5433x; 1.5433x over previous
//
#include <hip/hip_runtime.h>
#include <hip/hip_bf16.h>

// CapsuleLayer routing via bf16 MFMA. B=512,P=1152,N=10,T=16,D=8, 3 iters.
// s-pass GEMM1: s[b,nt] = sum_k Xb[b,k] * Wc[nt,k], k=(p,d), K=9216.
// agreement GEMM2: H[pd,nt] = sum_b Xt[pd,b] * Vt[nt,b]; then contract with W.
// Inputs are bf16-exact fp32 -> Xb/Xt conversion lossless; Wc=c*W and Vt
// rounding add ~2^-9 rel error (threshold 1.65e-2, fp32 margin was 3.9e-3).

typedef __attribute__((ext_vector_type(8))) short bfrag;   // 8 bf16 (4 VGPR)
typedef __attribute__((ext_vector_type(4))) float f32x4;

constexpr int B_ = 512, P_ = 1152, N_ = 10, T_ = 16, D_ = 8;
constexpr int NT_ = 160;
constexpr int K1_ = P_ * D_;            // 9216
constexpr int NKC_ = K1_ / 32;          // 288 k-chunks of 32
constexpr int KSPLIT_ = 24;             // split-K for GEMM1
constexpr int KPB_ = NKC_ / KSPLIT_;    // 12 chunks per block

__device__ __forceinline__ unsigned short f2bf(float f) {
    unsigned u = __float_as_uint(f);
    unsigned r = (u + 0x7fffu + ((u >> 16) & 1u)) >> 16;   // round-nearest-even
    return (unsigned short)r;
}

// ---- one-time: x fp32 [B][K1] -> Xb bf16 (same layout) ----------------------
__global__ __launch_bounds__(256) void k_xb(const float* __restrict__ x,
                                            unsigned short* __restrict__ Xb) {
    const size_t i = ((size_t)blockIdx.x * 256 + threadIdx.x) * 8;  // 589824 thr
    f32x4 a = *(const f32x4*)(x + i);
    f32x4 b = *(const f32x4*)(x + i + 4);
    unsigned w0 = f2bf(a.x) | ((unsigned)f2bf(a.y) << 16);
    unsigned w1 = f2bf(a.z) | ((unsigned)f2bf(a.w) << 16);
    unsigned w2 = f2bf(b.x) | ((unsigned)f2bf(b.y) << 16);
    unsigned w3 = f2bf(b.z) | ((unsigned)f2bf(b.w) << 16);
    uint4 v = make_uint4(w0, w1, w2, w3);
    *(uint4*)(Xb + i) = v;
}

// ---- one-time: Xt[pd][b] bf16 transpose of x ------------------------------
__global__ __launch_bounds__(256) void k_xt(const float* __restrict__ x,
                                            unsigned short* __restrict__ Xt) {
    __shared__ unsigned short tile[64][72];
    const int pd0 = blockIdx.x * 64, b0 = blockIdx.y * 64;
    const int c0 = threadIdx.x & 63, r0 = threadIdx.x >> 6;
#pragma unroll
    for (int i = 0; i < 16; ++i) {
        const int br = r0 + i * 4;
        tile[c0][br] = f2bf(x[(size_t)(b0 + br) * K1_ + pd0 + c0]);
    }
    __syncthreads();
#pragma unroll
    for (int i = 0; i < 16; ++i) {
        const int pr = r0 + i * 4;
        Xt[(size_t)(pd0 + pr) * B_ + b0 + c0] = tile[pr][c0];
    }
}

// ---- per-iter: Wc[kc][nt][32] bf16 = softmax(bbar)[p,n] * W[p,nt,d] --------
__global__ __launch_bounds__(256) void k_wc(const float* __restrict__ W,
                                            const float* __restrict__ bbar,
                                            unsigned short* __restrict__ Wc) {
    const int idx = blockIdx.x * 256 + threadIdx.x;    // 184320 = 720 blocks
    const int p = idx / NT_, nt = idx % NT_, n = nt >> 4;
    const float* br = bbar + (size_t)p * N_;
    float bv[N_], m = -1e30f;
#pragma unroll
    for (int k = 0; k < N_; ++k) { bv[k] = br[k]; m = fmaxf(m, bv[k]); }
    float sum = 0.f;
#pragma unroll
    for (int k = 0; k < N_; ++k) { bv[k] = __expf(bv[k] - m); sum += bv[k]; }
    const float c = bv[n] / sum;
    const float* wr = W + (size_t)idx * D_;
    f32x4 a = *(const f32x4*)wr;
    f32x4 b = *(const f32x4*)(wr + 4);
    unsigned w0 = f2bf(c * a.x) | ((unsigned)f2bf(c * a.y) << 16);
    unsigned w1 = f2bf(c * a.z) | ((unsigned)f2bf(c * a.w) << 16);
    unsigned w2 = f2bf(c * b.x) | ((unsigned)f2bf(c * b.y) << 16);
    unsigned w3 = f2bf(c * b.z) | ((unsigned)f2bf(c * b.w) << 16);
    uint4 v = make_uint4(w0, w1, w2, w3);
    *(uint4*)(Wc + (size_t)(p >> 2) * 5120 + nt * 32 + (p & 3) * 8) = v;
}

// ---- GEMM1: spart[ks][b][nt] partial of Xb x Wc^T. grid(32,24), 64 thr -----
// wave = 16 m-rows x 160 n. A: m=lane&15,k=q*8+j. B: n=lane&15,k=q*8+j.
__global__ __launch_bounds__(64) void k_s(const unsigned short* __restrict__ Xb,
                                          const unsigned short* __restrict__ Wc,
                                          float* __restrict__ spart) {
    const int lane = threadIdx.x;
    const int col = lane & 15, q = lane >> 4;
    const int m0 = blockIdx.x * 16;
    const int ks = blockIdx.y;
    f32x4 acc[10];
#pragma unroll
    for (int j = 0; j < 10; ++j) acc[j] = (f32x4){0.f, 0.f, 0.f, 0.f};

    const int kc0 = ks * KPB_;
    for (int kc = kc0; kc < kc0 + KPB_; ++kc) {
        bfrag a = *(const bfrag*)(Xb + (size_t)(m0 + col) * K1_ + kc * 32 + q * 8);
#pragma unroll
        for (int j = 0; j < 10; ++j) {
            bfrag b = *(const bfrag*)(Wc + (size_t)kc * 5120 + (j * 16 + col) * 32 + q * 8);
            acc[j] = __builtin_amdgcn_mfma_f32_16x16x32_bf16(a, b, acc[j], 0, 0, 0);
        }
    }
    float* dst = spart + (size_t)ks * B_ * NT_;
#pragma unroll
    for (int j = 0; j < 10; ++j)
#pragma unroll
        for (int r = 0; r < 4; ++r)
            dst[(size_t)(m0 + q * 4 + r) * NT_ + j * 16 + col] = acc[j][r];
}

// ---- reduce partials + squash; writes Vt bf16 (iters 0,1) or d_out (final) -
__global__ __launch_bounds__(256) void k_v(const float* __restrict__ spart,
                                           unsigned short* __restrict__ Vt,
                                           float* __restrict__ outp, int final_it) {
    const int t = blockIdx.x * 256 + threadIdx.x;   // 20480
    const int tq = t & 3, n = (t >> 2) % N_, b = t / 40;
    const size_t base = (size_t)b * NT_ + n * 16 + tq * 4;
    f32x4 a = (f32x4){0.f, 0.f, 0.f, 0.f};
#pragma unroll
    for (int ks = 0; ks < KSPLIT_; ++ks) {
        f32x4 u = *(const f32x4*)(spart + (size_t)ks * B_ * NT_ + base);
        a.x += u.x; a.y += u.y; a.z += u.z; a.w += u.w;
    }
    float sq = a.x * a.x + a.y * a.y + a.z * a.z + a.w * a.w;
    sq += __shfl_xor(sq, 1);
    sq += __shfl_xor(sq, 2);
    const float norm = sqrtf(sq);
    const float scale = sq / (1.0f + sq * (norm + 1e-9f));
    a.x *= scale; a.y *= scale; a.z *= scale; a.w *= scale;
    if (final_it) {
        *(f32x4*)(outp + base) = a;
    } else {
        const int nt = n * 16 + tq * 4;
        Vt[(size_t)(nt + 0) * B_ + b] = f2bf(a.x);
        Vt[(size_t)(nt + 1) * B_ + b] = f2bf(a.y);
        Vt[(size_t)(nt + 2) * B_ + b] = f2bf(a.z);
        Vt[(size_t)(nt + 3) * B_ + b] = f2bf(a.w);
    }
}

// ---- GEMM2: Ht[pd][nt] = sum_b Vt[nt,b] * Xt[pd,b]. grid 576, 64 thr -------
__global__ __launch_bounds__(64) void k_g(const unsigned short* __restrict__ Vt,
                                          const unsigned short* __restrict__ Xt,
                                          float* __restrict__ Ht) {
    const int lane = threadIdx.x;
    const int col = lane & 15, q = lane >> 4;
    const int pd0 = blockIdx.x * 16;
    f32x4 acc[10];
#pragma unroll
    for (int mt = 0; mt < 10; ++mt) acc[mt] = (f32x4){0.f, 0.f, 0.f, 0.f};
    for (int kc = 0; kc < 16; ++kc) {
        bfrag bf = *(const bfrag*)(Xt + (size_t)(pd0 + col) * B_ + kc * 32 + q * 8);
#pragma unroll
        for (int mt = 0; mt < 10; ++mt) {
            bfrag af = *(const bfrag*)(Vt + (size_t)(mt * 16 + col) * B_ + kc * 32 + q * 8);
            acc[mt] = __builtin_amdgcn_mfma_f32_16x16x32_bf16(af, bf, acc[mt], 0, 0, 0);
        }
    }
#pragma unroll
    for (int mt = 0; mt < 10; ++mt)
        *(f32x4*)(Ht + (size_t)(pd0 + col) * NT_ + mt * 16 + q * 4) = acc[mt];
}

// ---- agreement contraction: bbar[p,n] += (1/B) sum_{d,t} W * Ht ------------
__global__ __launch_bounds__(256) void k_a(const float* __restrict__ W,
                                           const float* __restrict__ Ht,
                                           float* __restrict__ bbar) {
    const int idx = blockIdx.x * 256 + threadIdx.x;   // 92160 = 360 blocks
    const int d = idx & 7, n = (idx >> 3) % N_, p = idx / 80;
    const float* hr = Ht + (size_t)(p * 8 + d) * NT_ + n * 16;
    float ht[16];
#pragma unroll
    for (int i = 0; i < 4; ++i) {
        f32x4 u = *(const f32x4*)(hr + i * 4);
        ht[i * 4 + 0] = u.x; ht[i * 4 + 1] = u.y; ht[i * 4 + 2] = u.z; ht[i * 4 + 3] = u.w;
    }
    float acc = 0.f;
#pragma unroll
    for (int t = 0; t < 16; ++t)
        acc = fmaf(W[((size_t)p * NT_ + n * 16 + t) * D_ + d], ht[t], acc);
    acc += __shfl_xor(acc, 1);
    acc += __shfl_xor(acc, 2);
    acc += __shfl_xor(acc, 4);
    if (d == 0) bbar[p * N_ + n] += acc * (1.0f / 512.0f);
}

extern "C" void kernel_launch(void* const* d_in, const int* in_sizes, int n_in,
                              void* d_out, int out_size, void* d_ws, size_t ws_size,
                              hipStream_t stream) {
    const float* x = (const float*)d_in[0];   // fp32 [B][P*D]
    const float* W = (const float*)d_in[1];   // fp32 [P][NT][D]

    char* w = (char*)d_ws;
    float* bbar = (float*)w;                                    // 46080 B
    unsigned short* Xb = (unsigned short*)(w + 46080);          // 9.44 MB
    unsigned short* Xt = Xb + (size_t)B_ * K1_;                 // 9.44 MB
    unsigned short* Wc = Xt + (size_t)B_ * K1_;                 // 2.95 MB
    unsigned short* Vt = Wc + (size_t)NKC_ * 5120;              // 160 KB
    float* spart = (float*)(Vt + (size_t)NT_ * B_);             // 7.86 MB
    float* Ht = spart;                                          // overlay (disjoint lifetime)
    // total 29.9 MB (proven ws >= 31.8 MB from round-3 mode-1 run)

    hipMemsetAsync(bbar, 0, (size_t)P_ * N_ * sizeof(float), stream);
    k_xb<<<dim3(2304), dim3(256), 0, stream>>>(x, Xb);
    k_xt<<<dim3(K1_ / 64, B_ / 64), dim3(256), 0, stream>>>(x, Xt);

    for (int it = 0; it < 3; ++it) {
        k_wc<<<dim3(720), dim3(256), 0, stream>>>(W, bbar, Wc);
        k_s<<<dim3(32, KSPLIT_), dim3(64), 0, stream>>>(Xb, Wc, spart);
        k_v<<<dim3(80), dim3(256), 0, stream>>>(spart, Vt, (float*)d_out, it == 2);
        if (it < 2) {
            k_g<<<dim3(576), dim3(64), 0, stream>>>(Vt, Xt, Ht);
            k_a<<<dim3(360), dim3(256), 0, stream>>>(W, Ht, bbar);
        }
    }
}